// Round 1
// baseline (1483.779 us; speedup 1.0000x reference)
//
#include <hip/hip_runtime.h>
#include <hip/hip_bf16.h>

typedef short short8 __attribute__((ext_vector_type(8)));
typedef float f32x4 __attribute__((ext_vector_type(4)));

#define LN_EPS 1e-5f

__device__ __forceinline__ unsigned short f2bf(float f) {
    unsigned int u = __builtin_bit_cast(unsigned int, f);
    unsigned int r = (u + 0x7FFFu + ((u >> 16) & 1u)) >> 16;
    return (unsigned short)r;
}

// ---------------- weight prep: fp32 [K][128] -> bf16 transposed [128][K] ----
__global__ __launch_bounds__(256) void prep_kernel(
    const float* __restrict__ W1, const float* __restrict__ W2,
    const float* __restrict__ W3, const float* __restrict__ W4,
    unsigned short* __restrict__ wt1, unsigned short* __restrict__ wt2,
    unsigned short* __restrict__ wt3, unsigned short* __restrict__ wt4)
{
    int idx = blockIdx.x * 256 + threadIdx.x;
    if (idx < 32768) {                       // W1: 256x128
        int k = idx >> 7, n = idx & 127;
        wt1[n * 256 + k] = f2bf(W1[idx]);
    } else if (idx < 49152) {                // W2: 128x128
        int j = idx - 32768; int k = j >> 7, n = j & 127;
        wt2[n * 128 + k] = f2bf(W2[j]);
    } else if (idx < 65536) {                // W3
        int j = idx - 49152; int k = j >> 7, n = j & 127;
        wt3[n * 128 + k] = f2bf(W3[j]);
    } else if (idx < 81920) {                // W4
        int j = idx - 65536; int k = j >> 7, n = j & 127;
        wt4[n * 128 + k] = f2bf(W4[j]);
    }
}

// ---------------- scatter-add: agg[r] += x[s] over edges ---------------------
__global__ __launch_bounds__(256) void scatter_kernel(
    const float4* __restrict__ x4, const int* __restrict__ ei,
    float* agg, int N, int E)
{
    long long t = (long long)blockIdx.x * 256 + threadIdx.x;
    int e = (int)(t >> 5);
    int c = (int)(t & 31);
    if (e >= E) return;
    // edge_index dtype detection: int64 has zero high words (values < 2^31)
    bool is64 = ((ei[1] | ei[3] | ei[5] | ei[7]) == 0);
    int s, r;
    if (is64) {
        const long long* e64 = (const long long*)ei;
        s = (int)e64[e]; r = (int)e64[E + e];
    } else {
        s = ei[e]; r = ei[E + e];
    }
    float4 v = x4[s * 32 + c];
    float* dst = agg + r * 128 + c * 4;
    unsafeAtomicAdd(dst + 0, v.x);
    unsafeAtomicAdd(dst + 1, v.y);
    unsafeAtomicAdd(dst + 2, v.z);
    unsafeAtomicAdd(dst + 3, v.w);
}

// ---------------- fused MLP + LayerNorm -------------------------------------
// Per block: 64 nodes. 4 waves, wave w owns output cols [w*32, w*32+32).
// LDS: region A 33792 B (h0 stride 264 bf16 / h2 stride 136 / h4 f32 stride 132)
//      region B 17408 B (h1 / h3, stride 136 bf16)

template<int K, bool RELU>
__device__ __forceinline__ void layer_bf16(
    const unsigned short* Hin, int sin,
    const unsigned short* __restrict__ Wt, const float* __restrict__ bias,
    unsigned short* Hout, int sout, int tid)
{
    int lane = tid & 63;
    int w = tid >> 6;
    int r0 = lane & 15, quad = lane >> 4;
    int col0 = w * 32 + r0;
    int col1 = w * 32 + 16 + r0;
    float bias0 = bias[col0], bias1 = bias[col1];
    f32x4 acc[4][2];
#pragma unroll
    for (int rt = 0; rt < 4; ++rt) { acc[rt][0] = 0.f; acc[rt][1] = 0.f; }
    const unsigned short* wrow0 = Wt + col0 * K + quad * 8;
    const unsigned short* wrow1 = Wt + col1 * K + quad * 8;
    const unsigned short* arow = Hin + r0 * sin + quad * 8;
#pragma unroll
    for (int ks = 0; ks < K / 32; ++ks) {
        short8 bf0 = *(const short8*)(wrow0 + ks * 32);
        short8 bf1 = *(const short8*)(wrow1 + ks * 32);
#pragma unroll
        for (int rt = 0; rt < 4; ++rt) {
            short8 af = *(const short8*)(arow + rt * 16 * sin + ks * 32);
            acc[rt][0] = __builtin_amdgcn_mfma_f32_16x16x32_bf16(af, bf0, acc[rt][0], 0, 0, 0);
            acc[rt][1] = __builtin_amdgcn_mfma_f32_16x16x32_bf16(af, bf1, acc[rt][1], 0, 0, 0);
        }
    }
#pragma unroll
    for (int rt = 0; rt < 4; ++rt) {
#pragma unroll
        for (int i = 0; i < 4; ++i) {
            int row = rt * 16 + quad * 4 + i;
            float v0 = acc[rt][0][i] + bias0;
            float v1 = acc[rt][1][i] + bias1;
            if (RELU) { v0 = fmaxf(v0, 0.f); v1 = fmaxf(v1, 0.f); }
            Hout[row * sout + col0] = f2bf(v0);
            Hout[row * sout + col1] = f2bf(v1);
        }
    }
}

__device__ __forceinline__ void layer_f32out(
    const unsigned short* Hin, int sin,
    const unsigned short* __restrict__ Wt, const float* __restrict__ bias,
    float* Hout, int sout, int tid)
{
    constexpr int K = 128;
    int lane = tid & 63;
    int w = tid >> 6;
    int r0 = lane & 15, quad = lane >> 4;
    int col0 = w * 32 + r0;
    int col1 = w * 32 + 16 + r0;
    float bias0 = bias[col0], bias1 = bias[col1];
    f32x4 acc[4][2];
#pragma unroll
    for (int rt = 0; rt < 4; ++rt) { acc[rt][0] = 0.f; acc[rt][1] = 0.f; }
    const unsigned short* wrow0 = Wt + col0 * K + quad * 8;
    const unsigned short* wrow1 = Wt + col1 * K + quad * 8;
    const unsigned short* arow = Hin + r0 * sin + quad * 8;
#pragma unroll
    for (int ks = 0; ks < K / 32; ++ks) {
        short8 bf0 = *(const short8*)(wrow0 + ks * 32);
        short8 bf1 = *(const short8*)(wrow1 + ks * 32);
#pragma unroll
        for (int rt = 0; rt < 4; ++rt) {
            short8 af = *(const short8*)(arow + rt * 16 * sin + ks * 32);
            acc[rt][0] = __builtin_amdgcn_mfma_f32_16x16x32_bf16(af, bf0, acc[rt][0], 0, 0, 0);
            acc[rt][1] = __builtin_amdgcn_mfma_f32_16x16x32_bf16(af, bf1, acc[rt][1], 0, 0, 0);
        }
    }
#pragma unroll
    for (int rt = 0; rt < 4; ++rt) {
#pragma unroll
        for (int i = 0; i < 4; ++i) {
            int row = rt * 16 + quad * 4 + i;
            Hout[row * sout + col0] = acc[rt][0][i] + bias0;
            Hout[row * sout + col1] = acc[rt][1][i] + bias1;
        }
    }
}

__global__ __launch_bounds__(256) void mlp_kernel(
    const float4* __restrict__ x4, const float4* agg4,
    const unsigned short* __restrict__ wt1, const unsigned short* __restrict__ wt2,
    const unsigned short* __restrict__ wt3, const unsigned short* __restrict__ wt4,
    const float* __restrict__ b1, const float* __restrict__ b2,
    const float* __restrict__ b3, const float* __restrict__ b4,
    const float* __restrict__ gamma, const float* __restrict__ beta,
    float4* out4, int N)
{
    __shared__ unsigned char smem[33792 + 17408];
    unsigned short* HA = (unsigned short*)smem;            // h0 (stride 264) / h2 (stride 136)
    unsigned short* HB = (unsigned short*)(smem + 33792);  // h1 / h3 (stride 136)
    float* H4 = (float*)smem;                              // h4 fp32 (stride 132)

    int tid = threadIdx.x;
    int node0 = blockIdx.x * 64;

    // ---- stage h0 = [bf16(x) | bf16(agg)] into LDS ----
#pragma unroll
    for (int j = 0; j < 8; ++j) {
        int idx = tid + j * 256;           // 0..2047
        int row = idx >> 5, c4 = idx & 31; // 64 rows x 32 float4
        int node = node0 + row;
        float4 vx = make_float4(0.f, 0.f, 0.f, 0.f);
        float4 va = make_float4(0.f, 0.f, 0.f, 0.f);
        if (node < N) {
            vx = x4[node * 32 + c4];
            va = agg4[node * 32 + c4];
        }
        unsigned short* p = HA + row * 264 + c4 * 4;
        p[0] = f2bf(vx.x); p[1] = f2bf(vx.y); p[2] = f2bf(vx.z); p[3] = f2bf(vx.w);
        unsigned short* q = p + 128;
        q[0] = f2bf(va.x); q[1] = f2bf(va.y); q[2] = f2bf(va.z); q[3] = f2bf(va.w);
    }
    __syncthreads();

    layer_bf16<256, true>(HA, 264, wt1, b1, HB, 136, tid);   // h0 -> h1
    __syncthreads();
    layer_bf16<128, true>(HB, 136, wt2, b2, HA, 136, tid);   // h1 -> h2
    __syncthreads();
    layer_bf16<128, true>(HA, 136, wt3, b3, HB, 136, tid);   // h2 -> h3
    __syncthreads();
    layer_f32out(HB, 136, wt4, b4, H4, 132, tid);            // h3 -> h4 (fp32)
    __syncthreads();

    // ---- LayerNorm: 4 threads per row, 32 cols each ----
    int row = tid >> 2;
    int part = tid & 3;
    const float* hr = H4 + row * 132 + part * 32;
    float s = 0.f, s2 = 0.f;
#pragma unroll
    for (int j = 0; j < 8; ++j) {
        float4 v = *(const float4*)(hr + j * 4);
        s  += v.x + v.y + v.z + v.w;
        s2 += v.x * v.x + v.y * v.y + v.z * v.z + v.w * v.w;
    }
    s  += __shfl_xor(s, 1);  s  += __shfl_xor(s, 2);
    s2 += __shfl_xor(s2, 1); s2 += __shfl_xor(s2, 2);
    float mu = s * (1.f / 128.f);
    float var = s2 * (1.f / 128.f) - mu * mu;
    float rstd = rsqrtf(fmaxf(var, 0.f) + LN_EPS);
    int node = node0 + row;
    if (node < N) {
#pragma unroll
        for (int j = 0; j < 8; ++j) {
            int c = part * 32 + j * 4;
            float4 v = *(const float4*)(hr + j * 4);
            float4 o;
            o.x = (v.x - mu) * rstd * gamma[c + 0] + beta[c + 0];
            o.y = (v.y - mu) * rstd * gamma[c + 1] + beta[c + 1];
            o.z = (v.z - mu) * rstd * gamma[c + 2] + beta[c + 2];
            o.w = (v.w - mu) * rstd * gamma[c + 3] + beta[c + 3];
            out4[node * 32 + part * 8 + j] = o;
        }
    }
}

extern "C" void kernel_launch(void* const* d_in, const int* in_sizes, int n_in,
                              void* d_out, int out_size, void* d_ws, size_t ws_size,
                              hipStream_t stream) {
    const float* x     = (const float*)d_in[0];
    const int*   edges = (const int*)d_in[1];
    const float* W1 = (const float*)d_in[2];
    const float* b1 = (const float*)d_in[3];
    const float* W2 = (const float*)d_in[4];
    const float* b2 = (const float*)d_in[5];
    const float* W3 = (const float*)d_in[6];
    const float* b3 = (const float*)d_in[7];
    const float* W4 = (const float*)d_in[8];
    const float* b4 = (const float*)d_in[9];
    const float* gamma = (const float*)d_in[10];
    const float* beta  = (const float*)d_in[11];

    int N = in_sizes[0] / 128;
    int E = in_sizes[1] / 2;

    // agg scratch lives in d_out (each mlp block only reads rows it later writes)
    float* agg = (float*)d_out;

    // ws: bf16 transposed weights
    unsigned short* wt1 = (unsigned short*)d_ws;                  // 128x256
    unsigned short* wt2 = wt1 + 128 * 256;                        // 128x128
    unsigned short* wt3 = wt2 + 128 * 128;
    unsigned short* wt4 = wt3 + 128 * 128;

    hipMemsetAsync(agg, 0, (size_t)N * 128 * sizeof(float), stream);
    prep_kernel<<<320, 256, 0, stream>>>(W1, W2, W3, W4, wt1, wt2, wt3, wt4);

    long long total_sc = (long long)E * 32;
    int sc_blocks = (int)((total_sc + 255) / 256);
    scatter_kernel<<<sc_blocks, 256, 0, stream>>>((const float4*)x, edges, agg, N, E);

    int mlp_blocks = (N + 63) / 64;
    mlp_kernel<<<mlp_blocks, 256, 0, stream>>>(
        (const float4*)x, (const float4*)agg,
        wt1, wt2, wt3, wt4, b1, b2, b3, b4, gamma, beta,
        (float4*)d_out, N);
}

// Round 2
// 293.989 us; speedup vs baseline: 5.0471x; 5.0471x over previous
//
#include <hip/hip_runtime.h>
#include <hip/hip_bf16.h>

typedef short short8 __attribute__((ext_vector_type(8)));
typedef float f32x4 __attribute__((ext_vector_type(4)));

#define LN_EPS 1e-5f

__device__ __forceinline__ unsigned short f2bf(float f) {
    unsigned int u = __builtin_bit_cast(unsigned int, f);
    unsigned int r = (u + 0x7FFFu + ((u >> 16) & 1u)) >> 16;
    return (unsigned short)r;
}

__device__ __forceinline__ bool edges_are_i64(const int* ei) {
    return ((ei[1] | ei[3] | ei[5] | ei[7]) == 0);
}

// ---------------- weight prep: fp32 [K][128] -> bf16 transposed [128][K] ----
__global__ __launch_bounds__(256) void prep_kernel(
    const float* __restrict__ W1, const float* __restrict__ W2,
    const float* __restrict__ W3, const float* __restrict__ W4,
    unsigned short* __restrict__ wt1, unsigned short* __restrict__ wt2,
    unsigned short* __restrict__ wt3, unsigned short* __restrict__ wt4)
{
    int idx = blockIdx.x * 256 + threadIdx.x;
    if (idx < 32768) {                       // W1: 256x128
        int k = idx >> 7, n = idx & 127;
        wt1[n * 256 + k] = f2bf(W1[idx]);
    } else if (idx < 49152) {                // W2: 128x128
        int j = idx - 32768; int k = j >> 7, n = j & 127;
        wt2[n * 128 + k] = f2bf(W2[j]);
    } else if (idx < 65536) {                // W3
        int j = idx - 49152; int k = j >> 7, n = j & 127;
        wt3[n * 128 + k] = f2bf(W3[j]);
    } else if (idx < 81920) {                // W4
        int j = idx - 65536; int k = j >> 7, n = j & 127;
        wt4[n * 128 + k] = f2bf(W4[j]);
    }
}

// ---------------- CSR build: histogram ----------------
__global__ __launch_bounds__(256) void hist_kernel(
    const int* __restrict__ ei, int* counts, int E)
{
    int e = blockIdx.x * 256 + threadIdx.x;
    if (e >= E) return;
    int r;
    if (edges_are_i64(ei)) r = (int)((const long long*)ei)[E + e];
    else                   r = ei[E + e];
    atomicAdd(&counts[r], 1);
}

// ---------------- 3-kernel exclusive scan over counts[N] ----------------
__global__ __launch_bounds__(256) void scan1_kernel(
    const int* __restrict__ counts, int* blockSums, int N)
{
    __shared__ int sd[256];
    int t = threadIdx.x;
    int i = blockIdx.x * 256 + t;
    sd[t] = (i < N) ? counts[i] : 0;
    __syncthreads();
    for (int d = 128; d > 0; d >>= 1) {
        if (t < d) sd[t] += sd[t + d];
        __syncthreads();
    }
    if (t == 0) blockSums[blockIdx.x] = sd[0];
}

__global__ __launch_bounds__(256) void scan2_kernel(
    int* blockSums, int* offsets, int nb, int N, int E)
{
    __shared__ int sd[256];
    int t = threadIdx.x;
    int v = (t < nb) ? blockSums[t] : 0;
    sd[t] = v;
    __syncthreads();
    for (int d = 1; d < 256; d <<= 1) {
        int add = (t >= d) ? sd[t - d] : 0;
        __syncthreads();
        sd[t] += add;
        __syncthreads();
    }
    if (t < nb) blockSums[t] = sd[t] - v;   // exclusive
    if (t == 0) offsets[N] = E;
}

__global__ __launch_bounds__(256) void scan3_kernel(
    const int* __restrict__ counts, const int* __restrict__ blockSums,
    int* offsets, int* cursor, int N)
{
    __shared__ int sd[256];
    int t = threadIdx.x;
    int i = blockIdx.x * 256 + t;
    int v = (i < N) ? counts[i] : 0;
    sd[t] = v;
    __syncthreads();
    for (int d = 1; d < 256; d <<= 1) {
        int add = (t >= d) ? sd[t - d] : 0;
        __syncthreads();
        sd[t] += add;
        __syncthreads();
    }
    if (i < N) {
        int off = blockSums[blockIdx.x] + sd[t] - v;   // exclusive
        offsets[i] = off;
        cursor[i] = off;
    }
}

// ---------------- place senders into CSR order ----------------
__global__ __launch_bounds__(256) void scatterpos_kernel(
    const int* __restrict__ ei, int* cursor, int* __restrict__ sorted, int E)
{
    int e = blockIdx.x * 256 + threadIdx.x;
    if (e >= E) return;
    int s, r;
    if (edges_are_i64(ei)) {
        const long long* e64 = (const long long*)ei;
        s = (int)e64[e]; r = (int)e64[E + e];
    } else {
        s = ei[e]; r = ei[E + e];
    }
    int pos = atomicAdd(&cursor[r], 1);
    sorted[pos] = s;
}

// ---------------- atomic-free segmented aggregation ----------------
// one wave per receiver; lane holds cols [2*lane, 2*lane+1]
__global__ __launch_bounds__(256) void aggregate_kernel(
    const float2* __restrict__ x2, const int* __restrict__ offsets,
    const int* __restrict__ sorted, float2* __restrict__ agg2, int N)
{
    int wave = threadIdx.x >> 6, lane = threadIdx.x & 63;
    int r = blockIdx.x * 4 + wave;
    if (r >= N) return;
    int beg = offsets[r], end = offsets[r + 1];
    float2 acc = make_float2(0.f, 0.f);
    for (int base = beg; base < end; base += 64) {
        int cnt = min(64, end - base);
        int idx = (base + lane < end) ? sorted[base + lane] : 0;
        for (int i = 0; i < cnt; ++i) {
            int s = __shfl(idx, i);
            float2 v = x2[s * 64 + lane];
            acc.x += v.x; acc.y += v.y;
        }
    }
    agg2[r * 64 + lane] = acc;
}

// ---------------- fused MLP + LayerNorm -------------------------------------
template<int K, bool RELU>
__device__ __forceinline__ void layer_bf16(
    const unsigned short* Hin, int sin,
    const unsigned short* __restrict__ Wt, const float* __restrict__ bias,
    unsigned short* Hout, int sout, int tid)
{
    int lane = tid & 63;
    int w = tid >> 6;
    int r0 = lane & 15, quad = lane >> 4;
    int col0 = w * 32 + r0;
    int col1 = w * 32 + 16 + r0;
    float bias0 = bias[col0], bias1 = bias[col1];
    f32x4 acc[4][2];
#pragma unroll
    for (int rt = 0; rt < 4; ++rt) { acc[rt][0] = 0.f; acc[rt][1] = 0.f; }
    const unsigned short* wrow0 = Wt + col0 * K + quad * 8;
    const unsigned short* wrow1 = Wt + col1 * K + quad * 8;
    const unsigned short* arow = Hin + r0 * sin + quad * 8;
#pragma unroll
    for (int ks = 0; ks < K / 32; ++ks) {
        short8 bf0 = *(const short8*)(wrow0 + ks * 32);
        short8 bf1 = *(const short8*)(wrow1 + ks * 32);
#pragma unroll
        for (int rt = 0; rt < 4; ++rt) {
            short8 af = *(const short8*)(arow + rt * 16 * sin + ks * 32);
            acc[rt][0] = __builtin_amdgcn_mfma_f32_16x16x32_bf16(af, bf0, acc[rt][0], 0, 0, 0);
            acc[rt][1] = __builtin_amdgcn_mfma_f32_16x16x32_bf16(af, bf1, acc[rt][1], 0, 0, 0);
        }
    }
#pragma unroll
    for (int rt = 0; rt < 4; ++rt) {
#pragma unroll
        for (int i = 0; i < 4; ++i) {
            int row = rt * 16 + quad * 4 + i;
            float v0 = acc[rt][0][i] + bias0;
            float v1 = acc[rt][1][i] + bias1;
            if (RELU) { v0 = fmaxf(v0, 0.f); v1 = fmaxf(v1, 0.f); }
            Hout[row * sout + col0] = f2bf(v0);
            Hout[row * sout + col1] = f2bf(v1);
        }
    }
}

__device__ __forceinline__ void layer_f32out(
    const unsigned short* Hin, int sin,
    const unsigned short* __restrict__ Wt, const float* __restrict__ bias,
    float* Hout, int sout, int tid)
{
    constexpr int K = 128;
    int lane = tid & 63;
    int w = tid >> 6;
    int r0 = lane & 15, quad = lane >> 4;
    int col0 = w * 32 + r0;
    int col1 = w * 32 + 16 + r0;
    float bias0 = bias[col0], bias1 = bias[col1];
    f32x4 acc[4][2];
#pragma unroll
    for (int rt = 0; rt < 4; ++rt) { acc[rt][0] = 0.f; acc[rt][1] = 0.f; }
    const unsigned short* wrow0 = Wt + col0 * K + quad * 8;
    const unsigned short* wrow1 = Wt + col1 * K + quad * 8;
    const unsigned short* arow = Hin + r0 * sin + quad * 8;
#pragma unroll
    for (int ks = 0; ks < K / 32; ++ks) {
        short8 bf0 = *(const short8*)(wrow0 + ks * 32);
        short8 bf1 = *(const short8*)(wrow1 + ks * 32);
#pragma unroll
        for (int rt = 0; rt < 4; ++rt) {
            short8 af = *(const short8*)(arow + rt * 16 * sin + ks * 32);
            acc[rt][0] = __builtin_amdgcn_mfma_f32_16x16x32_bf16(af, bf0, acc[rt][0], 0, 0, 0);
            acc[rt][1] = __builtin_amdgcn_mfma_f32_16x16x32_bf16(af, bf1, acc[rt][1], 0, 0, 0);
        }
    }
#pragma unroll
    for (int rt = 0; rt < 4; ++rt) {
#pragma unroll
        for (int i = 0; i < 4; ++i) {
            int row = rt * 16 + quad * 4 + i;
            Hout[row * sout + col0] = acc[rt][0][i] + bias0;
            Hout[row * sout + col1] = acc[rt][1][i] + bias1;
        }
    }
}

__global__ __launch_bounds__(256) void mlp_kernel(
    const float4* __restrict__ x4, const float4* agg4,
    const unsigned short* __restrict__ wt1, const unsigned short* __restrict__ wt2,
    const unsigned short* __restrict__ wt3, const unsigned short* __restrict__ wt4,
    const float* __restrict__ b1, const float* __restrict__ b2,
    const float* __restrict__ b3, const float* __restrict__ b4,
    const float* __restrict__ gamma, const float* __restrict__ beta,
    float4* out4, int N)
{
    __shared__ unsigned char smem[33792 + 17408];
    unsigned short* HA = (unsigned short*)smem;            // h0 (stride 264) / h2 (stride 136)
    unsigned short* HB = (unsigned short*)(smem + 33792);  // h1 / h3 (stride 136)
    float* H4 = (float*)smem;                              // h4 fp32 (stride 132)

    int tid = threadIdx.x;
    int node0 = blockIdx.x * 64;

#pragma unroll
    for (int j = 0; j < 8; ++j) {
        int idx = tid + j * 256;           // 0..2047
        int row = idx >> 5, c4 = idx & 31; // 64 rows x 32 float4
        int node = node0 + row;
        float4 vx = make_float4(0.f, 0.f, 0.f, 0.f);
        float4 va = make_float4(0.f, 0.f, 0.f, 0.f);
        if (node < N) {
            vx = x4[node * 32 + c4];
            va = agg4[node * 32 + c4];
        }
        unsigned short* p = HA + row * 264 + c4 * 4;
        p[0] = f2bf(vx.x); p[1] = f2bf(vx.y); p[2] = f2bf(vx.z); p[3] = f2bf(vx.w);
        unsigned short* q = p + 128;
        q[0] = f2bf(va.x); q[1] = f2bf(va.y); q[2] = f2bf(va.z); q[3] = f2bf(va.w);
    }
    __syncthreads();

    layer_bf16<256, true>(HA, 264, wt1, b1, HB, 136, tid);   // h0 -> h1
    __syncthreads();
    layer_bf16<128, true>(HB, 136, wt2, b2, HA, 136, tid);   // h1 -> h2
    __syncthreads();
    layer_bf16<128, true>(HA, 136, wt3, b3, HB, 136, tid);   // h2 -> h3
    __syncthreads();
    layer_f32out(HB, 136, wt4, b4, H4, 132, tid);            // h3 -> h4 (fp32)
    __syncthreads();

    int row = tid >> 2;
    int part = tid & 3;
    const float* hr = H4 + row * 132 + part * 32;
    float s = 0.f, s2 = 0.f;
#pragma unroll
    for (int j = 0; j < 8; ++j) {
        float4 v = *(const float4*)(hr + j * 4);
        s  += v.x + v.y + v.z + v.w;
        s2 += v.x * v.x + v.y * v.y + v.z * v.z + v.w * v.w;
    }
    s  += __shfl_xor(s, 1);  s  += __shfl_xor(s, 2);
    s2 += __shfl_xor(s2, 1); s2 += __shfl_xor(s2, 2);
    float mu = s * (1.f / 128.f);
    float var = s2 * (1.f / 128.f) - mu * mu;
    float rstd = rsqrtf(fmaxf(var, 0.f) + LN_EPS);
    int node = node0 + row;
    if (node < N) {
#pragma unroll
        for (int j = 0; j < 8; ++j) {
            int c = part * 32 + j * 4;
            float4 v = *(const float4*)(hr + j * 4);
            float4 o;
            o.x = (v.x - mu) * rstd * gamma[c + 0] + beta[c + 0];
            o.y = (v.y - mu) * rstd * gamma[c + 1] + beta[c + 1];
            o.z = (v.z - mu) * rstd * gamma[c + 2] + beta[c + 2];
            o.w = (v.w - mu) * rstd * gamma[c + 3] + beta[c + 3];
            out4[node * 32 + part * 8 + j] = o;
        }
    }
}

extern "C" void kernel_launch(void* const* d_in, const int* in_sizes, int n_in,
                              void* d_out, int out_size, void* d_ws, size_t ws_size,
                              hipStream_t stream) {
    const float* x     = (const float*)d_in[0];
    const int*   edges = (const int*)d_in[1];
    const float* W1 = (const float*)d_in[2];
    const float* b1 = (const float*)d_in[3];
    const float* W2 = (const float*)d_in[4];
    const float* b2 = (const float*)d_in[5];
    const float* W3 = (const float*)d_in[6];
    const float* b3 = (const float*)d_in[7];
    const float* W4 = (const float*)d_in[8];
    const float* b4 = (const float*)d_in[9];
    const float* gamma = (const float*)d_in[10];
    const float* beta  = (const float*)d_in[11];

    int N = in_sizes[0] / 128;
    int E = in_sizes[1] / 2;

    float* agg = (float*)d_out;   // agg scratch lives in d_out

    // ws layout
    unsigned short* wt1 = (unsigned short*)d_ws;          // 128x256
    unsigned short* wt2 = wt1 + 128 * 256;                // 128x128
    unsigned short* wt3 = wt2 + 128 * 128;
    unsigned short* wt4 = wt3 + 128 * 128;
    int* counts    = (int*)(wt4 + 128 * 128);             // N
    int* offsets   = counts + N;                          // N+1
    int* cursor    = offsets + N + 1;                     // N
    int* blockSums = cursor + N;                          // <=256
    int* sorted    = blockSums + 256;                     // E

    int nbN = (N + 255) / 256;   // scan blocks (must be <= 256)
    int nbE = (E + 255) / 256;

    hipMemsetAsync(counts, 0, (size_t)N * sizeof(int), stream);
    prep_kernel<<<320, 256, 0, stream>>>(W1, W2, W3, W4, wt1, wt2, wt3, wt4);

    hist_kernel<<<nbE, 256, 0, stream>>>(edges, counts, E);
    scan1_kernel<<<nbN, 256, 0, stream>>>(counts, blockSums, N);
    scan2_kernel<<<1, 256, 0, stream>>>(blockSums, offsets, nbN, N, E);
    scan3_kernel<<<nbN, 256, 0, stream>>>(counts, blockSums, offsets, cursor, N);
    scatterpos_kernel<<<nbE, 256, 0, stream>>>(edges, cursor, sorted, E);

    int agg_blocks = (N + 3) / 4;
    aggregate_kernel<<<agg_blocks, 256, 0, stream>>>(
        (const float2*)x, offsets, sorted, (float2*)agg, N);

    int mlp_blocks = (N + 63) / 64;
    mlp_kernel<<<mlp_blocks, 256, 0, stream>>>(
        (const float4*)x, (const float4*)agg,
        wt1, wt2, wt3, wt4, b1, b2, b3, b4, gamma, beta,
        (float4*)d_out, N);
}

// Round 3
// 276.311 us; speedup vs baseline: 5.3700x; 1.0640x over previous
//
#include <hip/hip_runtime.h>
#include <hip/hip_bf16.h>

typedef short short8 __attribute__((ext_vector_type(8)));
typedef float f32x4 __attribute__((ext_vector_type(4)));

#define LN_EPS 1e-5f

__device__ __forceinline__ unsigned short f2bf(float f) {
    unsigned int u = __builtin_bit_cast(unsigned int, f);
    unsigned int r = (u + 0x7FFFu + ((u >> 16) & 1u)) >> 16;
    return (unsigned short)r;
}
__device__ __forceinline__ float bf_lo(unsigned int v) {
    return __builtin_bit_cast(float, v << 16);
}
__device__ __forceinline__ float bf_hi(unsigned int v) {
    return __builtin_bit_cast(float, v & 0xFFFF0000u);
}

__device__ __forceinline__ bool edges_are_i64(const int* ei) {
    return ((ei[1] | ei[3] | ei[5] | ei[7]) == 0);
}

// ---------------- weight prep + counts zeroing ----------------
__global__ __launch_bounds__(256) void prep_kernel(
    const float* __restrict__ W1, const float* __restrict__ W2,
    const float* __restrict__ W3, const float* __restrict__ W4,
    unsigned short* __restrict__ wt1, unsigned short* __restrict__ wt2,
    unsigned short* __restrict__ wt3, unsigned short* __restrict__ wt4,
    int* __restrict__ counts, int N)
{
    int idx = blockIdx.x * 256 + threadIdx.x;
    if (idx < N) counts[idx] = 0;
    if (idx < 32768) {                       // W1: 256x128
        int k = idx >> 7, n = idx & 127;
        wt1[n * 256 + k] = f2bf(W1[idx]);
    } else if (idx < 49152) {                // W2: 128x128
        int j = idx - 32768; int k = j >> 7, n = j & 127;
        wt2[n * 128 + k] = f2bf(W2[j]);
    } else if (idx < 65536) {                // W3
        int j = idx - 49152; int k = j >> 7, n = j & 127;
        wt3[n * 128 + k] = f2bf(W3[j]);
    } else if (idx < 81920) {                // W4
        int j = idx - 65536; int k = j >> 7, n = j & 127;
        wt4[n * 128 + k] = f2bf(W4[j]);
    }
}

// ---------------- x fp32 -> bf16 ----------------
__global__ __launch_bounds__(256) void xcvt_kernel(
    const float4* __restrict__ x4, uint4* __restrict__ xb4, int total8)
{
    int i = blockIdx.x * 256 + threadIdx.x;
    if (i >= total8) return;
    float4 a = x4[i * 2], b = x4[i * 2 + 1];
    uint4 o;
    o.x = (unsigned int)f2bf(a.x) | ((unsigned int)f2bf(a.y) << 16);
    o.y = (unsigned int)f2bf(a.z) | ((unsigned int)f2bf(a.w) << 16);
    o.z = (unsigned int)f2bf(b.x) | ((unsigned int)f2bf(b.y) << 16);
    o.w = (unsigned int)f2bf(b.z) | ((unsigned int)f2bf(b.w) << 16);
    xb4[i] = o;
}

// ---------------- CSR build: histogram ----------------
__global__ __launch_bounds__(256) void hist_kernel(
    const int* __restrict__ ei, int* counts, int E)
{
    int e = blockIdx.x * 256 + threadIdx.x;
    if (e >= E) return;
    int r;
    if (edges_are_i64(ei)) r = (int)((const long long*)ei)[E + e];
    else                   r = ei[E + e];
    atomicAdd(&counts[r], 1);
}

// ---------------- 3-kernel exclusive scan over counts[N] ----------------
__global__ __launch_bounds__(256) void scan1_kernel(
    const int* __restrict__ counts, int* blockSums, int N)
{
    __shared__ int sd[256];
    int t = threadIdx.x;
    int i = blockIdx.x * 256 + t;
    sd[t] = (i < N) ? counts[i] : 0;
    __syncthreads();
    for (int d = 128; d > 0; d >>= 1) {
        if (t < d) sd[t] += sd[t + d];
        __syncthreads();
    }
    if (t == 0) blockSums[blockIdx.x] = sd[0];
}

__global__ __launch_bounds__(256) void scan2_kernel(
    int* blockSums, int* offsets, int nb, int N, int E)
{
    __shared__ int sd[256];
    int t = threadIdx.x;
    int v = (t < nb) ? blockSums[t] : 0;
    sd[t] = v;
    __syncthreads();
    for (int d = 1; d < 256; d <<= 1) {
        int add = (t >= d) ? sd[t - d] : 0;
        __syncthreads();
        sd[t] += add;
        __syncthreads();
    }
    if (t < nb) blockSums[t] = sd[t] - v;   // exclusive
    if (t == 0) offsets[N] = E;
}

__global__ __launch_bounds__(256) void scan3_kernel(
    const int* __restrict__ counts, const int* __restrict__ blockSums,
    int* offsets, int* cursor, int N)
{
    __shared__ int sd[256];
    int t = threadIdx.x;
    int i = blockIdx.x * 256 + t;
    int v = (i < N) ? counts[i] : 0;
    sd[t] = v;
    __syncthreads();
    for (int d = 1; d < 256; d <<= 1) {
        int add = (t >= d) ? sd[t - d] : 0;
        __syncthreads();
        sd[t] += add;
        __syncthreads();
    }
    if (i < N) {
        int off = blockSums[blockIdx.x] + sd[t] - v;   // exclusive
        offsets[i] = off;
        cursor[i] = off;
    }
}

// ---------------- place senders into CSR order ----------------
__global__ __launch_bounds__(256) void scatterpos_kernel(
    const int* __restrict__ ei, int* cursor, int* __restrict__ sorted, int E)
{
    int e = blockIdx.x * 256 + threadIdx.x;
    if (e >= E) return;
    int s, r;
    if (edges_are_i64(ei)) {
        const long long* e64 = (const long long*)ei;
        s = (int)e64[e]; r = (int)e64[E + e];
    } else {
        s = ei[e]; r = ei[E + e];
    }
    int pos = atomicAdd(&cursor[r], 1);
    sorted[pos] = s;
}

// ---------------- atomic-free segmented aggregation ----------------
// one wave per receiver; lane holds cols [2*lane, 2*lane+1]
// unroll-4 with independent accumulators to pipeline the gather latency
template<bool BF>
__global__ __launch_bounds__(256) void aggregate_kernel(
    const void* __restrict__ xsrc, const int* __restrict__ offsets,
    const int* __restrict__ sorted, float2* __restrict__ agg2, int N)
{
    int wave = threadIdx.x >> 6, lane = threadIdx.x & 63;
    int r = blockIdx.x * 4 + wave;
    if (r >= N) return;
    int beg = offsets[r], end = offsets[r + 1];
    const unsigned int* xb = (const unsigned int*)xsrc;
    const float2* x2 = (const float2*)xsrc;
    float ax0 = 0, ay0 = 0, ax1 = 0, ay1 = 0;
    float ax2 = 0, ay2 = 0, ax3 = 0, ay3 = 0;
    int i = beg;
    for (; i + 4 <= end; i += 4) {
        int s0 = sorted[i + 0];
        int s1 = sorted[i + 1];
        int s2 = sorted[i + 2];
        int s3 = sorted[i + 3];
        if constexpr (BF) {
            unsigned int v0 = xb[(size_t)s0 * 64 + lane];
            unsigned int v1 = xb[(size_t)s1 * 64 + lane];
            unsigned int v2 = xb[(size_t)s2 * 64 + lane];
            unsigned int v3 = xb[(size_t)s3 * 64 + lane];
            ax0 += bf_lo(v0); ay0 += bf_hi(v0);
            ax1 += bf_lo(v1); ay1 += bf_hi(v1);
            ax2 += bf_lo(v2); ay2 += bf_hi(v2);
            ax3 += bf_lo(v3); ay3 += bf_hi(v3);
        } else {
            float2 v0 = x2[(size_t)s0 * 64 + lane];
            float2 v1 = x2[(size_t)s1 * 64 + lane];
            float2 v2 = x2[(size_t)s2 * 64 + lane];
            float2 v3 = x2[(size_t)s3 * 64 + lane];
            ax0 += v0.x; ay0 += v0.y;
            ax1 += v1.x; ay1 += v1.y;
            ax2 += v2.x; ay2 += v2.y;
            ax3 += v3.x; ay3 += v3.y;
        }
    }
    for (; i < end; ++i) {
        int s = sorted[i];
        if constexpr (BF) {
            unsigned int v = xb[(size_t)s * 64 + lane];
            ax0 += bf_lo(v); ay0 += bf_hi(v);
        } else {
            float2 v = x2[(size_t)s * 64 + lane];
            ax0 += v.x; ay0 += v.y;
        }
    }
    float2 o;
    o.x = (ax0 + ax1) + (ax2 + ax3);
    o.y = (ay0 + ay1) + (ay2 + ay3);
    agg2[(size_t)r * 64 + lane] = o;
}

// ---------------- fused MLP + LayerNorm -------------------------------------
template<int K, bool RELU>
__device__ __forceinline__ void layer_bf16(
    const unsigned short* Hin, int sin,
    const unsigned short* __restrict__ Wt, const float* __restrict__ bias,
    unsigned short* Hout, int sout, int tid)
{
    int lane = tid & 63;
    int w = tid >> 6;
    int r0 = lane & 15, quad = lane >> 4;
    int col0 = w * 32 + r0;
    int col1 = w * 32 + 16 + r0;
    float bias0 = bias[col0], bias1 = bias[col1];
    f32x4 acc[4][2];
#pragma unroll
    for (int rt = 0; rt < 4; ++rt) { acc[rt][0] = 0.f; acc[rt][1] = 0.f; }
    const unsigned short* wrow0 = Wt + col0 * K + quad * 8;
    const unsigned short* wrow1 = Wt + col1 * K + quad * 8;
    const unsigned short* arow = Hin + r0 * sin + quad * 8;
#pragma unroll
    for (int ks = 0; ks < K / 32; ++ks) {
        short8 bf0 = *(const short8*)(wrow0 + ks * 32);
        short8 bf1 = *(const short8*)(wrow1 + ks * 32);
#pragma unroll
        for (int rt = 0; rt < 4; ++rt) {
            short8 af = *(const short8*)(arow + rt * 16 * sin + ks * 32);
            acc[rt][0] = __builtin_amdgcn_mfma_f32_16x16x32_bf16(af, bf0, acc[rt][0], 0, 0, 0);
            acc[rt][1] = __builtin_amdgcn_mfma_f32_16x16x32_bf16(af, bf1, acc[rt][1], 0, 0, 0);
        }
    }
#pragma unroll
    for (int rt = 0; rt < 4; ++rt) {
#pragma unroll
        for (int i = 0; i < 4; ++i) {
            int row = rt * 16 + quad * 4 + i;
            float v0 = acc[rt][0][i] + bias0;
            float v1 = acc[rt][1][i] + bias1;
            if (RELU) { v0 = fmaxf(v0, 0.f); v1 = fmaxf(v1, 0.f); }
            Hout[row * sout + col0] = f2bf(v0);
            Hout[row * sout + col1] = f2bf(v1);
        }
    }
}

__device__ __forceinline__ void layer_f32out(
    const unsigned short* Hin, int sin,
    const unsigned short* __restrict__ Wt, const float* __restrict__ bias,
    float* Hout, int sout, int tid)
{
    constexpr int K = 128;
    int lane = tid & 63;
    int w = tid >> 6;
    int r0 = lane & 15, quad = lane >> 4;
    int col0 = w * 32 + r0;
    int col1 = w * 32 + 16 + r0;
    float bias0 = bias[col0], bias1 = bias[col1];
    f32x4 acc[4][2];
#pragma unroll
    for (int rt = 0; rt < 4; ++rt) { acc[rt][0] = 0.f; acc[rt][1] = 0.f; }
    const unsigned short* wrow0 = Wt + col0 * K + quad * 8;
    const unsigned short* wrow1 = Wt + col1 * K + quad * 8;
    const unsigned short* arow = Hin + r0 * sin + quad * 8;
#pragma unroll
    for (int ks = 0; ks < K / 32; ++ks) {
        short8 bf0 = *(const short8*)(wrow0 + ks * 32);
        short8 bf1 = *(const short8*)(wrow1 + ks * 32);
#pragma unroll
        for (int rt = 0; rt < 4; ++rt) {
            short8 af = *(const short8*)(arow + rt * 16 * sin + ks * 32);
            acc[rt][0] = __builtin_amdgcn_mfma_f32_16x16x32_bf16(af, bf0, acc[rt][0], 0, 0, 0);
            acc[rt][1] = __builtin_amdgcn_mfma_f32_16x16x32_bf16(af, bf1, acc[rt][1], 0, 0, 0);
        }
    }
#pragma unroll
    for (int rt = 0; rt < 4; ++rt) {
#pragma unroll
        for (int i = 0; i < 4; ++i) {
            int row = rt * 16 + quad * 4 + i;
            Hout[row * sout + col0] = acc[rt][0][i] + bias0;
            Hout[row * sout + col1] = acc[rt][1][i] + bias1;
        }
    }
}

__global__ __launch_bounds__(256) void mlp_kernel(
    const float4* __restrict__ x4, const uint2* __restrict__ xb2, int hasxb,
    const float4* agg4,
    const unsigned short* __restrict__ wt1, const unsigned short* __restrict__ wt2,
    const unsigned short* __restrict__ wt3, const unsigned short* __restrict__ wt4,
    const float* __restrict__ b1, const float* __restrict__ b2,
    const float* __restrict__ b3, const float* __restrict__ b4,
    const float* __restrict__ gamma, const float* __restrict__ beta,
    float4* out4, int N)
{
    __shared__ unsigned char smem[33792 + 17408];
    unsigned short* HA = (unsigned short*)smem;            // h0 (stride 264) / h2 (stride 136)
    unsigned short* HB = (unsigned short*)(smem + 33792);  // h1 / h3 (stride 136)
    float* H4 = (float*)smem;                              // h4 fp32 (stride 132)

    int tid = threadIdx.x;
    int node0 = blockIdx.x * 64;

#pragma unroll
    for (int j = 0; j < 8; ++j) {
        int idx = tid + j * 256;           // 0..2047
        int row = idx >> 5, c4 = idx & 31; // 64 rows x 32 chunks of 4 cols
        int node = node0 + row;
        unsigned short* p = HA + row * 264 + c4 * 4;
        if (hasxb) {
            uint2 vx = make_uint2(0u, 0u);
            if (node < N) vx = xb2[(size_t)node * 32 + c4];
            *(uint2*)p = vx;               // 4 bf16 cols, direct copy
        } else {
            float4 vx = make_float4(0.f, 0.f, 0.f, 0.f);
            if (node < N) vx = x4[node * 32 + c4];
            p[0] = f2bf(vx.x); p[1] = f2bf(vx.y); p[2] = f2bf(vx.z); p[3] = f2bf(vx.w);
        }
        float4 va = make_float4(0.f, 0.f, 0.f, 0.f);
        if (node < N) va = agg4[node * 32 + c4];
        unsigned short* q = p + 128;
        q[0] = f2bf(va.x); q[1] = f2bf(va.y); q[2] = f2bf(va.z); q[3] = f2bf(va.w);
    }
    __syncthreads();

    layer_bf16<256, true>(HA, 264, wt1, b1, HB, 136, tid);   // h0 -> h1
    __syncthreads();
    layer_bf16<128, true>(HB, 136, wt2, b2, HA, 136, tid);   // h1 -> h2
    __syncthreads();
    layer_bf16<128, true>(HA, 136, wt3, b3, HB, 136, tid);   // h2 -> h3
    __syncthreads();
    layer_f32out(HB, 136, wt4, b4, H4, 132, tid);            // h3 -> h4 (fp32)
    __syncthreads();

    int row = tid >> 2;
    int part = tid & 3;
    const float* hr = H4 + row * 132 + part * 32;
    float s = 0.f, s2 = 0.f;
#pragma unroll
    for (int j = 0; j < 8; ++j) {
        float4 v = *(const float4*)(hr + j * 4);
        s  += v.x + v.y + v.z + v.w;
        s2 += v.x * v.x + v.y * v.y + v.z * v.z + v.w * v.w;
    }
    s  += __shfl_xor(s, 1);  s  += __shfl_xor(s, 2);
    s2 += __shfl_xor(s2, 1); s2 += __shfl_xor(s2, 2);
    float mu = s * (1.f / 128.f);
    float var = s2 * (1.f / 128.f) - mu * mu;
    float rstd = rsqrtf(fmaxf(var, 0.f) + LN_EPS);
    int node = node0 + row;
    if (node < N) {
#pragma unroll
        for (int j = 0; j < 8; ++j) {
            int c = part * 32 + j * 4;
            float4 v = *(const float4*)(hr + j * 4);
            float4 o;
            o.x = (v.x - mu) * rstd * gamma[c + 0] + beta[c + 0];
            o.y = (v.y - mu) * rstd * gamma[c + 1] + beta[c + 1];
            o.z = (v.z - mu) * rstd * gamma[c + 2] + beta[c + 2];
            o.w = (v.w - mu) * rstd * gamma[c + 3] + beta[c + 3];
            out4[node * 32 + part * 8 + j] = o;
        }
    }
}

extern "C" void kernel_launch(void* const* d_in, const int* in_sizes, int n_in,
                              void* d_out, int out_size, void* d_ws, size_t ws_size,
                              hipStream_t stream) {
    const float* x     = (const float*)d_in[0];
    const int*   edges = (const int*)d_in[1];
    const float* W1 = (const float*)d_in[2];
    const float* b1 = (const float*)d_in[3];
    const float* W2 = (const float*)d_in[4];
    const float* b2 = (const float*)d_in[5];
    const float* W3 = (const float*)d_in[6];
    const float* b3 = (const float*)d_in[7];
    const float* W4 = (const float*)d_in[8];
    const float* b4 = (const float*)d_in[9];
    const float* gamma = (const float*)d_in[10];
    const float* beta  = (const float*)d_in[11];

    int N = in_sizes[0] / 128;
    int E = in_sizes[1] / 2;

    float* agg = (float*)d_out;   // agg scratch lives in d_out (row-exact reuse, no race)

    // ws layout
    unsigned char* ws = (unsigned char*)d_ws;
    unsigned short* wt1 = (unsigned short*)ws;            // 128x256
    unsigned short* wt2 = wt1 + 128 * 256;                // 128x128
    unsigned short* wt3 = wt2 + 128 * 128;
    unsigned short* wt4 = wt3 + 128 * 128;
    size_t off = (size_t)(128 * 256 + 3 * 128 * 128) * 2; // 163840 B

    size_t xb_bytes = (size_t)N * 128 * 2;
    size_t int_bytes = (size_t)(3 * N + 1 + 256 + E) * 4;
    bool hasxb = (ws_size >= off + xb_bytes + int_bytes + 1024);

    unsigned short* xb = nullptr;
    if (hasxb) { xb = (unsigned short*)(ws + off); off += xb_bytes; }
    int* counts    = (int*)(ws + off);
    int* offsets   = counts + N;
    int* cursor    = offsets + N + 1;
    int* blockSums = cursor + N;
    int* sorted    = blockSums + 256;

    int nbN = (N + 255) / 256;   // scan blocks (must be <= 256)
    int nbE = (E + 255) / 256;

    prep_kernel<<<320, 256, 0, stream>>>(W1, W2, W3, W4, wt1, wt2, wt3, wt4, counts, N);
    if (hasxb) {
        int total8 = N * 16;  // N*128/8
        xcvt_kernel<<<(total8 + 255) / 256, 256, 0, stream>>>(
            (const float4*)x, (uint4*)xb, total8);
    }

    hist_kernel<<<nbE, 256, 0, stream>>>(edges, counts, E);
    scan1_kernel<<<nbN, 256, 0, stream>>>(counts, blockSums, N);
    scan2_kernel<<<1, 256, 0, stream>>>(blockSums, offsets, nbN, N, E);
    scan3_kernel<<<nbN, 256, 0, stream>>>(counts, blockSums, offsets, cursor, N);
    scatterpos_kernel<<<nbE, 256, 0, stream>>>(edges, cursor, sorted, E);

    int agg_blocks = (N + 3) / 4;
    if (hasxb)
        aggregate_kernel<true><<<agg_blocks, 256, 0, stream>>>(
            (const void*)xb, offsets, sorted, (float2*)agg, N);
    else
        aggregate_kernel<false><<<agg_blocks, 256, 0, stream>>>(
            (const void*)x, offsets, sorted, (float2*)agg, N);

    int mlp_blocks = (N + 63) / 64;
    mlp_kernel<<<mlp_blocks, 256, 0, stream>>>(
        (const float4*)x, (const uint2*)xb, hasxb ? 1 : 0,
        (const float4*)agg,
        wt1, wt2, wt3, wt4, b1, b2, b3, b4, gamma, beta,
        (float4*)d_out, N);
}